// Round 19
// baseline (180.255 us; speedup 1.0000x reference)
//
#include <hip/hip_runtime.h>

#define TSEQ 2048
#define CDIM 1024
#define NH 16
#define HS 64
#define BATCH 4

typedef __attribute__((ext_vector_type(8))) short short8;
typedef __attribute__((ext_vector_type(4))) short s16x4;
typedef __attribute__((ext_vector_type(4))) float f32x4;

__device__ __forceinline__ short f2bf(float f) {
    unsigned u = __builtin_bit_cast(unsigned, f);
    unsigned r = (u + 0x7fffu + ((u >> 16) & 1u)) >> 16;
    return (short)r;
}

__device__ __forceinline__ void gload_lds16(const void* g, void* l) {
    __builtin_amdgcn_global_load_lds((const __attribute__((address_space(1))) void*)g,
                                     (__attribute__((address_space(3))) void*)l, 16, 0, 0);
}

#define FENCE() asm volatile("" ::: "memory")

// ---- merged prep: blocks 0..8191 = x->bf16; 8192..9215 = W transpose+convert ----
__global__ void prep(const float* __restrict__ x, short* __restrict__ xb,
                     const float* __restrict__ Wk, const float* __restrict__ Wq,
                     const float* __restrict__ Wv, const float* __restrict__ Wp,
                     short* __restrict__ Wcat, short* __restrict__ Wpt) {
    __shared__ float tl[64][65];
    const int bid = blockIdx.x, t = threadIdx.x;
    if (bid < 8192) {  // x -> bf16 (float4 per thread)
        int i = bid * 256 + t;
        float4 v = ((const float4*)x)[i];
        s16x4 r;
        r[0] = f2bf(v.x); r[1] = f2bf(v.y); r[2] = f2bf(v.z); r[3] = f2bf(v.w);
        ((s16x4*)xb)[i] = r;
        return;
    }
    const int widx = bid - 8192;          // 0..1023
    const int z = widx >> 8, rem = widx & 255;
    const int k0 = (rem & 15) * 64, n0 = (rem >> 4) * 64;
    const float* src; short* dst;
    if (z == 0)      { src = Wq; dst = Wcat; }
    else if (z == 1) { src = Wk; dst = Wcat + 1048576; }
    else if (z == 2) { src = Wv; dst = Wcat + 2097152; }
    else             { src = Wp; dst = Wpt; }
    const int tx = t & 63, ty = t >> 6;
#pragma unroll
    for (int i = 0; i < 16; ++i) {
        int r = i * 4 + ty;
        tl[r][tx] = src[(size_t)(k0 + r) * CDIM + n0 + tx];
    }
    __syncthreads();
#pragma unroll
    for (int i = 0; i < 16; ++i) {
        int r = i * 4 + ty;
        dst[(size_t)(n0 + r) * CDIM + k0 + tx] = f2bf(tl[tx][r]);
    }
}

// ==== QKV GEMM: 256x96 tile, 8 waves (4M x 2N, wave 64x48) — r7/r12-proven ====
__global__ __launch_bounds__(512, 4) void gemm96(const short* __restrict__ A,
                                                 const short* __restrict__ Bt,
                                                 const float* __restrict__ bq,
                                                 const float* __restrict__ bk,
                                                 const float* __restrict__ bv,
                                                 float alphaQ,
                                                 short* __restrict__ C,   // [8192][3072] Q,K
                                                 short* __restrict__ Vt) {
    __shared__ short As[256 * 64];
    __shared__ short Bs[96 * 64];
    const int t = threadIdx.x;
    const int lane = t & 63, w = t >> 6;
    const int lr = lane & 15, lg = lane >> 4;
    const int wr = w >> 1, wc = w & 1;           // 4M x 2N waves
    const int tl = (blockIdx.x & 7) * 128 + (blockIdx.x >> 3);  // XCD chunking
    const int mbase = (tl >> 5) * 256, nbase = (tl & 31) * 96;
    f32x4 acc[4][3] = {};
    for (int k0 = 0; k0 < 1024; k0 += 64) {
#pragma unroll
        for (int i = 0; i < 4; ++i) {            // A: 2048 chunks
            int chunk = i * 512 + t;
            int r = chunk >> 3, c = chunk & 7;
            int cl = c ^ (r & 7);
            gload_lds16(A + (size_t)(mbase + r) * 1024 + k0 + cl * 8, As + chunk * 8);
        }
        {                                        // B: 768 chunks
            int r = t >> 3, c = t & 7;
            int cl = c ^ (r & 7);
            gload_lds16(Bt + (size_t)(nbase + r) * 1024 + k0 + cl * 8, Bs + t * 8);
            if (t < 256) {
                int chunk = 512 + t;
                int r2 = chunk >> 3, c2 = chunk & 7;
                int cl2 = c2 ^ (r2 & 7);
                gload_lds16(Bt + (size_t)(nbase + r2) * 1024 + k0 + cl2 * 8, Bs + chunk * 8);
            }
        }
        __syncthreads();
#pragma unroll
        for (int ks = 0; ks < 2; ++ks) {
            short8 a[4], b[3];
#pragma unroll
            for (int mi = 0; mi < 4; ++mi) {
                int row = wr * 64 + mi * 16 + lr;
                int ch = (ks * 4 + lg) ^ (row & 7);
                a[mi] = *(const short8*)(As + row * 64 + ch * 8);
            }
#pragma unroll
            for (int ni = 0; ni < 3; ++ni) {
                int row = wc * 48 + ni * 16 + lr;
                int ch = (ks * 4 + lg) ^ (row & 7);
                b[ni] = *(const short8*)(Bs + row * 64 + ch * 8);
            }
#pragma unroll
            for (int mi = 0; mi < 4; ++mi)
#pragma unroll
                for (int ni = 0; ni < 3; ++ni)
                    acc[mi][ni] = __builtin_amdgcn_mfma_f32_16x16x32_bf16(a[mi], b[ni],
                                                                          acc[mi][ni], 0, 0, 0);
        }
        __syncthreads();
    }
    const int btok = mbase & (TSEQ - 1);
    const int bidx = mbase >> 11;
#pragma unroll
    for (int mi = 0; mi < 4; ++mi) {
#pragma unroll
        for (int ni = 0; ni < 3; ++ni) {
            const int col = nbase + wc * 48 + ni * 16 + lr;
            const float bvv = (col < 1024) ? bq[col]
                            : (col < 2048) ? bk[col - 1024] : bv[col - 2048];
            if (col >= 2048) {  // V: transposed store (4 consecutive tokens, 8B packed)
                const int dfull = col - 2048;
                const int tok0 = btok + wr * 64 + mi * 16 + lg * 4;
                s16x4 pk;
#pragma unroll
                for (int ii = 0; ii < 4; ++ii) pk[ii] = f2bf(acc[mi][ni][ii] + bvv);
                *(s16x4*)(Vt + (size_t)(bidx * 1024 + dfull) * TSEQ + tok0) = pk;
            } else {
                const float alpha = (col < 1024) ? alphaQ : 1.0f;
#pragma unroll
                for (int ii = 0; ii < 4; ++ii) {
                    const int row = mbase + wr * 64 + mi * 16 + lg * 4 + ii;
                    C[(size_t)row * 3072 + col] = f2bf((acc[mi][ni][ii] + bvv) * alpha);
                }
            }
        }
    }
}

// ---- proj GEMM (proven): C[M,N=1024] = A @ Bt^T + bias, fp32 out ----
__global__ __launch_bounds__(256) void gemm_bt(const short* __restrict__ A,
                                               const short* __restrict__ Bt,
                                               const float* __restrict__ bias,
                                               float* __restrict__ Cout) {
    __shared__ short As[128 * 64];
    __shared__ short Bs[128 * 64];
    const int t = threadIdx.x;
    const int lane = t & 63, w = t >> 6;
    const int lr = lane & 15, lg = lane >> 4;
    const int wr = w >> 1, wc = w & 1;
    const int mbase = blockIdx.y * 128, nbase = blockIdx.x * 128;
    f32x4 acc[4][4] = {};
    for (int k0 = 0; k0 < 1024; k0 += 64) {
#pragma unroll
        for (int i = 0; i < 4; ++i) {
            int chunk = i * 256 + t;
            int r = chunk >> 3, c = chunk & 7;
            int cl = c ^ (r & 7);
            gload_lds16(A + (size_t)(mbase + r) * 1024 + k0 + cl * 8, As + chunk * 8);
            gload_lds16(Bt + (size_t)(nbase + r) * 1024 + k0 + cl * 8, Bs + chunk * 8);
        }
        __syncthreads();
#pragma unroll
        for (int ks = 0; ks < 2; ++ks) {
            short8 a[4], b[4];
#pragma unroll
            for (int mi = 0; mi < 4; ++mi) {
                int row = wr * 64 + mi * 16 + lr;
                int ch = (ks * 4 + lg) ^ (row & 7);
                a[mi] = *(const short8*)(As + row * 64 + ch * 8);
            }
#pragma unroll
            for (int ni = 0; ni < 4; ++ni) {
                int row = wc * 64 + ni * 16 + lr;
                int ch = (ks * 4 + lg) ^ (row & 7);
                b[ni] = *(const short8*)(Bs + row * 64 + ch * 8);
            }
#pragma unroll
            for (int mi = 0; mi < 4; ++mi)
#pragma unroll
                for (int ni = 0; ni < 4; ++ni)
                    acc[mi][ni] = __builtin_amdgcn_mfma_f32_16x16x32_bf16(a[mi], b[ni],
                                                                          acc[mi][ni], 0, 0, 0);
        }
        __syncthreads();
    }
#pragma unroll
    for (int mi = 0; mi < 4; ++mi) {
#pragma unroll
        for (int ni = 0; ni < 4; ++ni) {
            int col = nbase + wc * 64 + ni * 16 + lr;
            float bvv = bias[col];
#pragma unroll
            for (int i = 0; i < 4; ++i) {
                int row = mbase + wr * 64 + mi * 16 + lg * 4 + i;
                Cout[(size_t)row * 1024 + col] = acc[mi][ni][i] + bvv;
            }
        }
    }
}

// -------- causal flash attention: KVBLK=128 (two 64-halves per barrier pair) --------
// 512 blocks = 64 bh x 8 pairs; block pb runs units {15-pb, pb} => 17 tile-iterations
// (vs 34 at KVBLK=64): half the barriers/vmcnt/stage-issues.  LDS: K 2x16K + V 2x16K +
// Pl 16K = 80 KB -> 2 blocks/CU = 16 waves/CU (same occupancy as r18).  Per-wave math
// per 64-kv half is the r18 body in identical order -> bit-identical output.
__global__ __launch_bounds__(512, 2) void attn(const short* __restrict__ QKV,
                                               const short* __restrict__ Vt,
                                               short* __restrict__ Y) {
    __shared__ short Kl[2][128 * 64];   // [kv 0..127][d 0..63], swizzled 8-chunks
    __shared__ short Vl[2][64 * 128];   // [d 0..63][kv 0..127], swizzled 16-chunks
    __shared__ short Pl[8][16 * 64];
    const int t = threadIdx.x, lane = t & 63, w = t >> 6;  // w 0..7
    const int lr = lane & 15, lg = lane >> 4;
    const int bid = blockIdx.x;
    const int cx = bid & 7, sx = bid >> 3;       // XCD chunking: 8 bh per XCD
    const int bh = cx * 8 + (sx >> 3), pb = sx & 7;
    const int b = bh >> 4, h = bh & 15;
    const size_t rowbase = (size_t)b * TSEQ;
    const float SHIFT2 = 17.31234049f;  // 12 * log2(e)
    // K stage: 1024 chunks of 8 shorts; thread t does chunks t, t+512.
    const int krA = t >> 3, krB = 64 + (t >> 3);           // kv rows (krA&7 == krB&7)
    const int kcl = (t & 7) ^ (krA & 7);                    // swizzled 8-chunk
    // V stage: 1024 chunks of 8 shorts (rows d=0..63, 16 chunks/row); t, t+512.
    const int vrA = t >> 4, vrB = 32 + (t >> 4);            // d rows (vrA&7 == vrB&7)
    const int vclA = (t & 15) ^ (vrA & 7);                  // swizzled 16-chunk
    const short* Kg = QKV + 1024 + h * HS;

#define STAGE(bf, j0n) do { \
    gload_lds16(Kg + (rowbase + (j0n) + krA) * 3072 + kcl * 8, &Kl[bf][t * 8]); \
    gload_lds16(Kg + (rowbase + (j0n) + krB) * 3072 + kcl * 8, &Kl[bf][(512 + t) * 8]); \
    gload_lds16(Vt + (size_t)(bh * 64 + vrA) * TSEQ + (j0n) + vclA * 8, &Vl[bf][t * 8]); \
    gload_lds16(Vt + (size_t)(bh * 64 + vrB) * TSEQ + (j0n) + vclA * 8, \
                &Vl[bf][(512 + t) * 8]); \
} while (0)

    const int useg0 = 15 - pb, useg1 = pb;
    for (int sg = 0; sg < 2; ++sg) {
        const int u = sg ? useg1 : useg0;
        const int q0w = u * 128 + w * 16;
        const int niter = u + 1;  // tiles of 128 kv
        short8 qf[2];
#pragma unroll
        for (int ks = 0; ks < 2; ++ks)
            qf[ks] = *(const short8*)(QKV + (rowbase + q0w + lr) * 3072 + h * HS +
                                      ks * 32 + lg * 8);
        float l_i[4] = {0.f, 0.f, 0.f, 0.f};
        f32x4 o[4] = {};
        STAGE(0, 0);  // prologue: tile 0 -> buf 0 (4 loads/thread)
        int buf = 0;
        for (int jt = 0; jt < niter; ++jt) {
            if (jt + 1 < niter) {
                STAGE(buf ^ 1, (jt + 1) * 128);
                asm volatile("s_waitcnt vmcnt(4)" ::: "memory");  // tile jt complete
            } else {
                asm volatile("s_waitcnt vmcnt(0)" ::: "memory");
            }
            __builtin_amdgcn_s_barrier();
            FENCE();
#pragma unroll
            for (int hf = 0; hf < 2; ++hf) {  // two 64-kv halves, no barrier between
                const int j0 = jt * 128 + hf * 64;
                if (j0 <= q0w + 15) {
                    f32x4 s[4];
                    __builtin_amdgcn_s_setprio(1);
#pragma unroll
                    for (int nt = 0; nt < 4; ++nt) {
                        s[nt] = f32x4{-SHIFT2, -SHIFT2, -SHIFT2, -SHIFT2};
                        if (j0 + nt * 16 <= q0w + 15) {  // skip fully-masked sub-tiles
                            const int kr = hf * 64 + nt * 16 + lr;  // kr&7 == (nt*16+lr)&7
#pragma unroll
                            for (int ks = 0; ks < 2; ++ks) {
                                short8 kf = *(const short8*)(&Kl[buf][kr * 64 +
                                                    (((ks * 4 + lg) ^ (kr & 7)) * 8)]);
                                s[nt] = __builtin_amdgcn_mfma_f32_16x16x32_bf16(
                                    qf[ks], kf, s[nt], 0, 0, 0);
                            }
                        }
                    }
                    __builtin_amdgcn_s_setprio(0);
                    if (j0 + 63 > q0w) {  // half contains this wave's diagonal
#pragma unroll
                        for (int nt = 0; nt < 4; ++nt)
#pragma unroll
                            for (int i = 0; i < 4; ++i) {
                                int kv = j0 + nt * 16 + lr;
                                int q = q0w + lg * 4 + i;
                                if (kv > q) s[nt][i] = -__builtin_inff();
                            }
                    }
#pragma unroll
                    for (int i = 0; i < 4; ++i) {
                        const int ql = lg * 4 + i;
                        float pt[4];
#pragma unroll
                        for (int nt = 0; nt < 4; ++nt) {
                            float p = __builtin_amdgcn_exp2f(s[nt][i]);
                            unsigned uu = __builtin_bit_cast(unsigned, p);
                            int chv = ((nt * 2 + (lr >> 3)) ^ (ql & 7));
                            Pl[w][ql * 64 + chv * 8 + (lr & 7)] = (short)(uu >> 16);
                            pt[nt] = p;
                        }
                        l_i[i] += (pt[0] + pt[1]) + (pt[2] + pt[3]);
                    }
                    short8 pf[2];
#pragma unroll
                    for (int ks = 0; ks < 2; ++ks)
                        pf[ks] = *(const short8*)(&Pl[w][lr * 64 +
                                                  (((ks * 4 + lg) ^ (lr & 7)) * 8)]);
                    __builtin_amdgcn_s_setprio(1);
#pragma unroll
                    for (int nd = 0; nd < 4; ++nd)
#pragma unroll
                        for (int ks = 0; ks < 2; ++ks) {
                            const int vr = nd * 16 + lr;            // d row
                            const int vc = (hf * 8 + ks * 4 + lg) ^ (vr & 7);
                            short8 vf = *(const short8*)(&Vl[buf][vr * 128 + vc * 8]);
                            o[nd] = __builtin_amdgcn_mfma_f32_16x16x32_bf16(
                                pf[ks], vf, o[nd], 0, 0, 0);
                        }
                    __builtin_amdgcn_s_setprio(0);
                }
            }
            FENCE();
            __builtin_amdgcn_s_barrier();  // WAR: buf reads done before next stage into it
            buf ^= 1;
        }
#pragma unroll
        for (int i = 0; i < 4; ++i) {
            float l = l_i[i];
            l += __shfl_xor(l, 1);
            l += __shfl_xor(l, 2);
            l += __shfl_xor(l, 4);
            l += __shfl_xor(l, 8);
            float inv = 1.0f / l;
            int q = q0w + lg * 4 + i;
#pragma unroll
            for (int nd = 0; nd < 4; ++nd)
                Y[(rowbase + q) * 1024 + h * HS + nd * 16 + lr] = f2bf(o[nd][i] * inv);
        }
        __syncthreads();  // LDS safe for next segment's tile-0 staging
    }
#undef STAGE
}

extern "C" void kernel_launch(void* const* d_in, const int* in_sizes, int n_in,
                              void* d_out, int out_size, void* d_ws, size_t ws_size,
                              hipStream_t stream) {
    const float* x  = (const float*)d_in[0];
    const float* Wk = (const float*)d_in[1];
    const float* bk = (const float*)d_in[2];
    const float* Wq = (const float*)d_in[3];
    const float* bq = (const float*)d_in[4];
    const float* Wv = (const float*)d_in[5];
    const float* bv = (const float*)d_in[6];
    const float* Wp = (const float*)d_in[7];
    const float* bp = (const float*)d_in[8];
    float* out = (float*)d_out;
    char* ws = (char*)d_ws;
    const size_t MB = 1024 * 1024;
    short* xb   = (short*)(ws);            // 16 MB (reused as Y after QKV GEMM)
    short* Wcat = (short*)(ws + 16 * MB);  // 6 MB: [Wq^T; Wk^T; Wv^T]
    short* Wpt  = (short*)(ws + 22 * MB);  // 2 MB
    short* QKVb = (short*)(ws + 24 * MB);  // 48 MB: [8192][3072] (V-cols unused)
    short* Yb   = xb;
    short* VtT  = (short*)d_out;           // 16 MB scratch in d_out: [64][64][2048]

    // Q prescale folds 1/sqrt(64) AND log2(e) (scores in log2 units for exp2 softmax)
    const float alphaQ = 0.125f * 1.44269504088896f;

    prep<<<9216, 256, 0, stream>>>(x, xb, Wk, Wq, Wv, Wp, Wcat, Wpt);
    gemm96<<<1024, 512, 0, stream>>>(xb, Wcat, bq, bk, bv, alphaQ, QKVb, VtT);
    attn<<<512, 512, 0, stream>>>(QKVb, VtT, Yb);
    gemm_bt<<<dim3(8, 64), 256, 0, stream>>>(Yb, Wpt, bp, out);
}

// Round 20
// 160.424 us; speedup vs baseline: 1.1236x; 1.1236x over previous
//
#include <hip/hip_runtime.h>

#define TSEQ 2048
#define CDIM 1024
#define NH 16
#define HS 64
#define BATCH 4

typedef __attribute__((ext_vector_type(8))) short short8;
typedef __attribute__((ext_vector_type(4))) short s16x4;
typedef __attribute__((ext_vector_type(4))) float f32x4;

__device__ __forceinline__ short f2bf(float f) {
    unsigned u = __builtin_bit_cast(unsigned, f);
    unsigned r = (u + 0x7fffu + ((u >> 16) & 1u)) >> 16;
    return (short)r;
}

__device__ __forceinline__ void gload_lds16(const void* g, void* l) {
    __builtin_amdgcn_global_load_lds((const __attribute__((address_space(1))) void*)g,
                                     (__attribute__((address_space(3))) void*)l, 16, 0, 0);
}

#define FENCE() asm volatile("" ::: "memory")

// ---- merged prep: blocks 0..8191 = x->bf16; 8192..9215 = W transpose+convert ----
__global__ void prep(const float* __restrict__ x, short* __restrict__ xb,
                     const float* __restrict__ Wk, const float* __restrict__ Wq,
                     const float* __restrict__ Wv, const float* __restrict__ Wp,
                     short* __restrict__ Wcat, short* __restrict__ Wpt) {
    __shared__ float tl[64][65];
    const int bid = blockIdx.x, t = threadIdx.x;
    if (bid < 8192) {  // x -> bf16 (float4 per thread)
        int i = bid * 256 + t;
        float4 v = ((const float4*)x)[i];
        s16x4 r;
        r[0] = f2bf(v.x); r[1] = f2bf(v.y); r[2] = f2bf(v.z); r[3] = f2bf(v.w);
        ((s16x4*)xb)[i] = r;
        return;
    }
    const int widx = bid - 8192;          // 0..1023
    const int z = widx >> 8, rem = widx & 255;
    const int k0 = (rem & 15) * 64, n0 = (rem >> 4) * 64;
    const float* src; short* dst;
    if (z == 0)      { src = Wq; dst = Wcat; }
    else if (z == 1) { src = Wk; dst = Wcat + 1048576; }
    else if (z == 2) { src = Wv; dst = Wcat + 2097152; }
    else             { src = Wp; dst = Wpt; }
    const int tx = t & 63, ty = t >> 6;
#pragma unroll
    for (int i = 0; i < 16; ++i) {
        int r = i * 4 + ty;
        tl[r][tx] = src[(size_t)(k0 + r) * CDIM + n0 + tx];
    }
    __syncthreads();
#pragma unroll
    for (int i = 0; i < 16; ++i) {
        int r = i * 4 + ty;
        dst[(size_t)(n0 + r) * CDIM + k0 + tx] = f2bf(tl[tx][r]);
    }
}

// ==== QKV GEMM: 256x96 tile, 8 waves (4M x 2N, wave 64x48) — r7/r12-proven ====
__global__ __launch_bounds__(512, 4) void gemm96(const short* __restrict__ A,
                                                 const short* __restrict__ Bt,
                                                 const float* __restrict__ bq,
                                                 const float* __restrict__ bk,
                                                 const float* __restrict__ bv,
                                                 float alphaQ,
                                                 short* __restrict__ C,   // [8192][3072] Q,K
                                                 short* __restrict__ Vt) {
    __shared__ short As[256 * 64];
    __shared__ short Bs[96 * 64];
    const int t = threadIdx.x;
    const int lane = t & 63, w = t >> 6;
    const int lr = lane & 15, lg = lane >> 4;
    const int wr = w >> 1, wc = w & 1;           // 4M x 2N waves
    const int tl = (blockIdx.x & 7) * 128 + (blockIdx.x >> 3);  // XCD chunking
    const int mbase = (tl >> 5) * 256, nbase = (tl & 31) * 96;
    f32x4 acc[4][3] = {};
    for (int k0 = 0; k0 < 1024; k0 += 64) {
#pragma unroll
        for (int i = 0; i < 4; ++i) {            // A: 2048 chunks
            int chunk = i * 512 + t;
            int r = chunk >> 3, c = chunk & 7;
            int cl = c ^ (r & 7);
            gload_lds16(A + (size_t)(mbase + r) * 1024 + k0 + cl * 8, As + chunk * 8);
        }
        {                                        // B: 768 chunks
            int r = t >> 3, c = t & 7;
            int cl = c ^ (r & 7);
            gload_lds16(Bt + (size_t)(nbase + r) * 1024 + k0 + cl * 8, Bs + t * 8);
            if (t < 256) {
                int chunk = 512 + t;
                int r2 = chunk >> 3, c2 = chunk & 7;
                int cl2 = c2 ^ (r2 & 7);
                gload_lds16(Bt + (size_t)(nbase + r2) * 1024 + k0 + cl2 * 8, Bs + chunk * 8);
            }
        }
        __syncthreads();
#pragma unroll
        for (int ks = 0; ks < 2; ++ks) {
            short8 a[4], b[3];
#pragma unroll
            for (int mi = 0; mi < 4; ++mi) {
                int row = wr * 64 + mi * 16 + lr;
                int ch = (ks * 4 + lg) ^ (row & 7);
                a[mi] = *(const short8*)(As + row * 64 + ch * 8);
            }
#pragma unroll
            for (int ni = 0; ni < 3; ++ni) {
                int row = wc * 48 + ni * 16 + lr;
                int ch = (ks * 4 + lg) ^ (row & 7);
                b[ni] = *(const short8*)(Bs + row * 64 + ch * 8);
            }
#pragma unroll
            for (int mi = 0; mi < 4; ++mi)
#pragma unroll
                for (int ni = 0; ni < 3; ++ni)
                    acc[mi][ni] = __builtin_amdgcn_mfma_f32_16x16x32_bf16(a[mi], b[ni],
                                                                          acc[mi][ni], 0, 0, 0);
        }
        __syncthreads();
    }
    const int btok = mbase & (TSEQ - 1);
    const int bidx = mbase >> 11;
#pragma unroll
    for (int mi = 0; mi < 4; ++mi) {
#pragma unroll
        for (int ni = 0; ni < 3; ++ni) {
            const int col = nbase + wc * 48 + ni * 16 + lr;
            const float bvv = (col < 1024) ? bq[col]
                            : (col < 2048) ? bk[col - 1024] : bv[col - 2048];
            if (col >= 2048) {  // V: transposed store (4 consecutive tokens, 8B packed)
                const int dfull = col - 2048;
                const int tok0 = btok + wr * 64 + mi * 16 + lg * 4;
                s16x4 pk;
#pragma unroll
                for (int ii = 0; ii < 4; ++ii) pk[ii] = f2bf(acc[mi][ni][ii] + bvv);
                *(s16x4*)(Vt + (size_t)(bidx * 1024 + dfull) * TSEQ + tok0) = pk;
            } else {
                const float alpha = (col < 1024) ? alphaQ : 1.0f;
#pragma unroll
                for (int ii = 0; ii < 4; ++ii) {
                    const int row = mbase + wr * 64 + mi * 16 + lg * 4 + ii;
                    C[(size_t)row * 3072 + col] = f2bf((acc[mi][ni][ii] + bvv) * alpha);
                }
            }
        }
    }
}

// ---- proj GEMM (proven): C[M,N=1024] = A @ Bt^T + bias, fp32 out ----
__global__ __launch_bounds__(256) void gemm_bt(const short* __restrict__ A,
                                               const short* __restrict__ Bt,
                                               const float* __restrict__ bias,
                                               float* __restrict__ Cout) {
    __shared__ short As[128 * 64];
    __shared__ short Bs[128 * 64];
    const int t = threadIdx.x;
    const int lane = t & 63, w = t >> 6;
    const int lr = lane & 15, lg = lane >> 4;
    const int wr = w >> 1, wc = w & 1;
    const int mbase = blockIdx.y * 128, nbase = blockIdx.x * 128;
    f32x4 acc[4][4] = {};
    for (int k0 = 0; k0 < 1024; k0 += 64) {
#pragma unroll
        for (int i = 0; i < 4; ++i) {
            int chunk = i * 256 + t;
            int r = chunk >> 3, c = chunk & 7;
            int cl = c ^ (r & 7);
            gload_lds16(A + (size_t)(mbase + r) * 1024 + k0 + cl * 8, As + chunk * 8);
            gload_lds16(Bt + (size_t)(nbase + r) * 1024 + k0 + cl * 8, Bs + chunk * 8);
        }
        __syncthreads();
#pragma unroll
        for (int ks = 0; ks < 2; ++ks) {
            short8 a[4], b[4];
#pragma unroll
            for (int mi = 0; mi < 4; ++mi) {
                int row = wr * 64 + mi * 16 + lr;
                int ch = (ks * 4 + lg) ^ (row & 7);
                a[mi] = *(const short8*)(As + row * 64 + ch * 8);
            }
#pragma unroll
            for (int ni = 0; ni < 4; ++ni) {
                int row = wc * 64 + ni * 16 + lr;
                int ch = (ks * 4 + lg) ^ (row & 7);
                b[ni] = *(const short8*)(Bs + row * 64 + ch * 8);
            }
#pragma unroll
            for (int mi = 0; mi < 4; ++mi)
#pragma unroll
                for (int ni = 0; ni < 4; ++ni)
                    acc[mi][ni] = __builtin_amdgcn_mfma_f32_16x16x32_bf16(a[mi], b[ni],
                                                                          acc[mi][ni], 0, 0, 0);
        }
        __syncthreads();
    }
#pragma unroll
    for (int mi = 0; mi < 4; ++mi) {
#pragma unroll
        for (int ni = 0; ni < 4; ++ni) {
            int col = nbase + wc * 64 + ni * 16 + lr;
            float bvv = bias[col];
#pragma unroll
            for (int i = 0; i < 4; ++i) {
                int row = mbase + wr * 64 + mi * 16 + lg * 4 + i;
                Cout[(size_t)row * 1024 + col] = acc[mi][ni][i] + bvv;
            }
        }
    }
}

// -------- causal flash attention: 8 waves, 128-row units, paired + counted vmcnt --------
// 512 blocks = 64 bh x 8 pairs; block pb handles units {15-pb, pb} (34 tiles each).
// VALU-trimmed softmax: SHIFT2 folded into the QK accumulator INIT (MFMA C-in is an
// add -> shift is free); l_i accumulated from fp32 p (numerator keeps truncated-bf16 P;
// ~1e-3 relative denominator shift, far under threshold).
__global__ __launch_bounds__(512, 3) void attn(const short* __restrict__ QKV,
                                               const short* __restrict__ Vt,
                                               short* __restrict__ Y) {
    __shared__ short Kl[2][64 * 64];
    __shared__ short Vl[2][64 * 64];
    __shared__ short Pl[8][16 * 64];
    const int t = threadIdx.x, lane = t & 63, w = t >> 6;  // w 0..7
    const int lr = lane & 15, lg = lane >> 4;
    const int bid = blockIdx.x;
    const int cx = bid & 7, sx = bid >> 3;       // XCD chunking: 8 bh per XCD
    const int bh = cx * 8 + (sx >> 3), pb = sx & 7;
    const int b = bh >> 4, h = bh & 15;
    const size_t rowbase = (size_t)b * TSEQ;
    const float SHIFT2 = 17.31234049f;  // 12 * log2(e)
    const int sr = t >> 3, sc = t & 7, scl = sc ^ (sr & 7);
    const short* Kg = QKV + 1024 + h * HS;

#define STAGE(bf, j0n) do { \
    gload_lds16(Kg + (rowbase + (j0n) + sr) * 3072 + scl * 8, &Kl[bf][t * 8]); \
    gload_lds16(Vt + (size_t)(bh * 64 + sr) * TSEQ + (j0n) + scl * 8, &Vl[bf][t * 8]); \
} while (0)

    const int useg0 = 15 - pb, useg1 = pb;
    for (int sg = 0; sg < 2; ++sg) {
        const int u = sg ? useg1 : useg0;
        const int q0w = u * 128 + w * 16;
        const int niter = 2 * u + 2;
        short8 qf[2];
#pragma unroll
        for (int ks = 0; ks < 2; ++ks)
            qf[ks] = *(const short8*)(QKV + (rowbase + q0w + lr) * 3072 + h * HS +
                                      ks * 32 + lg * 8);
        float l_i[4] = {0.f, 0.f, 0.f, 0.f};
        f32x4 o[4] = {};
        STAGE(0, 0);  // prologue: tile 0 -> buf 0 (2 loads/thread)
        int buf = 0;
        for (int jt = 0; jt < niter; ++jt) {
            const int j0 = jt * 64;
            if (jt + 1 < niter) {
                STAGE(buf ^ 1, j0 + 64);
                asm volatile("s_waitcnt vmcnt(2)" ::: "memory");  // tile jt complete
            } else {
                asm volatile("s_waitcnt vmcnt(0)" ::: "memory");
            }
            __builtin_amdgcn_s_barrier();
            FENCE();
            if (j0 <= q0w + 15) {
                f32x4 s[4];
                __builtin_amdgcn_s_setprio(1);
#pragma unroll
                for (int nt = 0; nt < 4; ++nt) {
                    s[nt] = f32x4{-SHIFT2, -SHIFT2, -SHIFT2, -SHIFT2};  // shift rides C-in
                    if (j0 + nt * 16 <= q0w + 15) {  // skip fully-masked sub-tiles
#pragma unroll
                        for (int ks = 0; ks < 2; ++ks) {
                            short8 kf = *(const short8*)(&Kl[buf][(nt * 16 + lr) * 64 +
                                                        (((ks * 4 + lg) ^ (lr & 7)) * 8)]);
                            s[nt] = __builtin_amdgcn_mfma_f32_16x16x32_bf16(qf[ks], kf,
                                                                            s[nt], 0, 0, 0);
                        }
                    }
                }
                __builtin_amdgcn_s_setprio(0);
                if (j0 + 63 > q0w) {  // tile contains this wave's diagonal: causal mask
#pragma unroll
                    for (int nt = 0; nt < 4; ++nt)
#pragma unroll
                        for (int i = 0; i < 4; ++i) {
                            int kv = j0 + nt * 16 + lr;
                            int q = q0w + lg * 4 + i;
                            if (kv > q) s[nt][i] = -__builtin_inff();
                        }
                }
#pragma unroll
                for (int i = 0; i < 4; ++i) {
                    const int ql = lg * 4 + i;
                    float pt[4];
#pragma unroll
                    for (int nt = 0; nt < 4; ++nt) {
                        float p = __builtin_amdgcn_exp2f(s[nt][i]);  // shift pre-folded
                        unsigned uu = __builtin_bit_cast(unsigned, p);
                        int chv = ((nt * 2 + (lr >> 3)) ^ (ql & 7));
                        Pl[w][ql * 64 + chv * 8 + (lr & 7)] = (short)(uu >> 16);  // trunc bf16
                        pt[nt] = p;  // fp32 accumulate (no truncation re-read)
                    }
                    l_i[i] += (pt[0] + pt[1]) + (pt[2] + pt[3]);
                }
                short8 pf[2];
#pragma unroll
                for (int ks = 0; ks < 2; ++ks)
                    pf[ks] = *(const short8*)(&Pl[w][lr * 64 +
                                                     (((ks * 4 + lg) ^ (lr & 7)) * 8)]);
                __builtin_amdgcn_s_setprio(1);
#pragma unroll
                for (int nd = 0; nd < 4; ++nd)
#pragma unroll
                    for (int ks = 0; ks < 2; ++ks) {
                        short8 vf = *(const short8*)(&Vl[buf][(nd * 16 + lr) * 64 +
                                                    (((ks * 4 + lg) ^ (lr & 7)) * 8)]);
                        o[nd] = __builtin_amdgcn_mfma_f32_16x16x32_bf16(pf[ks], vf,
                                                                        o[nd], 0, 0, 0);
                    }
                __builtin_amdgcn_s_setprio(0);
            }
            FENCE();
            __builtin_amdgcn_s_barrier();  // WAR: buf reads done before next stage into it
            buf ^= 1;
        }
#pragma unroll
        for (int i = 0; i < 4; ++i) {
            float l = l_i[i];
            l += __shfl_xor(l, 1);
            l += __shfl_xor(l, 2);
            l += __shfl_xor(l, 4);
            l += __shfl_xor(l, 8);
            float inv = 1.0f / l;
            int q = q0w + lg * 4 + i;
#pragma unroll
            for (int nd = 0; nd < 4; ++nd)
                Y[(rowbase + q) * 1024 + h * HS + nd * 16 + lr] = f2bf(o[nd][i] * inv);
        }
        __syncthreads();  // LDS safe for next segment's tile-0 staging
    }
#undef STAGE
}

extern "C" void kernel_launch(void* const* d_in, const int* in_sizes, int n_in,
                              void* d_out, int out_size, void* d_ws, size_t ws_size,
                              hipStream_t stream) {
    const float* x  = (const float*)d_in[0];
    const float* Wk = (const float*)d_in[1];
    const float* bk = (const float*)d_in[2];
    const float* Wq = (const float*)d_in[3];
    const float* bq = (const float*)d_in[4];
    const float* Wv = (const float*)d_in[5];
    const float* bv = (const float*)d_in[6];
    const float* Wp = (const float*)d_in[7];
    const float* bp = (const float*)d_in[8];
    float* out = (float*)d_out;
    char* ws = (char*)d_ws;
    const size_t MB = 1024 * 1024;
    short* xb   = (short*)(ws);            // 16 MB (reused as Y after QKV GEMM)
    short* Wcat = (short*)(ws + 16 * MB);  // 6 MB: [Wq^T; Wk^T; Wv^T]
    short* Wpt  = (short*)(ws + 22 * MB);  // 2 MB
    short* QKVb = (short*)(ws + 24 * MB);  // 48 MB: [8192][3072] (V-cols unused)
    short* Yb   = xb;
    short* VtT  = (short*)d_out;           // 16 MB scratch in d_out: [64][64][2048]

    // Q prescale folds 1/sqrt(64) AND log2(e) (scores in log2 units for exp2 softmax)
    const float alphaQ = 0.125f * 1.44269504088896f;

    prep<<<9216, 256, 0, stream>>>(x, xb, Wk, Wq, Wv, Wp, Wcat, Wpt);
    gemm96<<<1024, 512, 0, stream>>>(xb, Wcat, bq, bk, bv, alphaQ, QKVb, VtT);
    attn<<<512, 512, 0, stream>>>(QKVb, VtT, Yb);
    gemm_bt<<<dim3(8, 64), 256, 0, stream>>>(Yb, Wpt, bp, out);
}